// Round 2
// baseline (956.627 us; speedup 1.0000x reference)
//
#include <hip/hip_runtime.h>
#include <hip/hip_bf16.h>
#include <stdint.h>
#include <math.h>

typedef uint32_t u32;
typedef __hip_bfloat16 bf16t;
typedef __attribute__((ext_vector_type(8))) short short8;
typedef __attribute__((ext_vector_type(4))) float f32x4;

// ---- JAX PRNG semantics ----
// 1: jax_threefry_partitionable=True (modern JAX default):
//    split(key,n)[i] = (o0(key;0,i), o1(key;0,i))
//    random_bits32(key,shape)[f] = o0(key;0,f) ^ o1(key;0,f)
// 0: legacy: split via iota(2n) halves-pairing; random_bits via iota(size) halves.
// Both: randint pre-splits its key and uses k2's bits; span=8192 pow2 -> bits & 8191
// (multiplier = (2^16 % 8192)^2 % 8192 = 0). fold_in(key,d) = threefry(key, (0,d)).
#define PRNG_MODE 1

// ================= threefry2x32 (bit-exact vs JAX) =================
__host__ __device__ __forceinline__ void tf2(u32 k0, u32 k1, u32 c0, u32 c1, u32& o0, u32& o1) {
  const u32 ks2 = k0 ^ k1 ^ 0x1BD11BDAu;
  u32 x0 = c0 + k0, x1 = c1 + k1;
#define TFROT(v,r) (((v)<<(r))|((v)>>(32-(r))))
#define TFR(r) { x0 += x1; x1 = TFROT(x1,r); x1 ^= x0; }
  TFR(13) TFR(15) TFR(26) TFR(6)   x0 += k1;  x1 += ks2 + 1u;
  TFR(17) TFR(29) TFR(16) TFR(24)  x0 += ks2; x1 += k0 + 2u;
  TFR(13) TFR(15) TFR(26) TFR(6)   x0 += k0;  x1 += k1 + 3u;
  TFR(17) TFR(29) TFR(16) TFR(24)  x0 += k1;  x1 += ks2 + 4u;
  TFR(13) TFR(15) TFR(26) TFR(6)   x0 += ks2; x1 += k0 + 5u;
#undef TFR
#undef TFROT
  o0 = x0; o1 = x1;
}

// uniform[0,1) for jax.random.uniform(key,(8192,1)) element i
__device__ __forceinline__ float unif_row(u32 ka, u32 kb, int i) {
  u32 o0, o1, b;
#if PRNG_MODE == 1
  tf2(ka, kb, 0u, (u32)i, o0, o1); b = o0 ^ o1;
#else
  if (i < 4096) { tf2(ka, kb, (u32)i, (u32)(4096 + i), o0, o1); b = o0; }
  else          { tf2(ka, kb, (u32)(i - 4096), (u32)i, o0, o1); b = o1; }
#endif
  return __uint_as_float(0x3F800000u | (b >> 9)) - 1.0f;
}

// randint(key,(8192,1024),0,8192) flat element f; ka/kb is the randint's
// PRE-SPLIT second subkey (host computes split(k5)[1]).
__device__ __forceinline__ int ridx_fn(u32 ka, u32 kb, u32 f) {
#if PRNG_MODE == 1
  u32 o0, o1; tf2(ka, kb, 0u, f, o0, o1); return (int)((o0 ^ o1) & 8191u);
#else
  const u32 H = 4194304u;  // (8192*1024)/2
  u32 o0, o1;
  if (f < H) { tf2(ka, kb, f, H + f, o0, o1); return (int)(o0 & 8191u); }
  tf2(ka, kb, f - H, f, o0, o1); return (int)(o1 & 8191u);
#endif
}

// host: split(key, 2)
static inline void split2(u32 ka, u32 kb, u32* kA, u32* kB) {
#if PRNG_MODE == 1
  u32 a0, a1, b0, b1;
  tf2(ka, kb, 0u, 0u, a0, a1);
  tf2(ka, kb, 0u, 1u, b0, b1);
  kA[0] = a0; kA[1] = a1; kB[0] = b0; kB[1] = b1;
#else
  u32 a0, a1, b0, b1;
  tf2(ka, kb, 0u, 2u, a0, a1);   // pairs (0,2),(1,3) from iota(4) halves
  tf2(ka, kb, 1u, 3u, b0, b1);
  kA[0] = a0; kA[1] = b0; kB[0] = a1; kB[1] = b1;
#endif
}

// host: split(key, 6) -> 6 keys
static inline void split6(u32 ka, u32 kb, u32 out[6][2]) {
#if PRNG_MODE == 1
  for (u32 i = 0; i < 6; i++) { u32 o0, o1; tf2(ka, kb, 0u, i, o0, o1); out[i][0] = o0; out[i][1] = o1; }
#else
  u32 xa[6], xb[6];
  for (u32 i = 0; i < 6; i++) tf2(ka, kb, i, 6u + i, xa[i], xb[i]);  // iota(12) halves
  out[0][0] = xa[0]; out[0][1] = xa[1];
  out[1][0] = xa[2]; out[1][1] = xa[3];
  out[2][0] = xa[4]; out[2][1] = xa[5];
  out[3][0] = xb[0]; out[3][1] = xb[1];
  out[4][0] = xb[2]; out[4][1] = xb[3];
  out[5][0] = xb[4]; out[5][1] = xb[5];
#endif
}

// host: jax.random.randint(key, (), 0, 8192) — splits key, uses k2's scalar bits
static inline int scalar_randint8192(u32 ka, u32 kb) {
  u32 kA[2], kB[2];
  split2(ka, kb, kA, kB);
  u32 o0, o1;
  tf2(kB[0], kB[1], 0u, 0u, o0, o1);
#if PRNG_MODE == 1
  return (int)((o0 ^ o1) & 8191u);
#else
  return (int)(o0 & 8191u);  // legacy scalar: size-1 odd -> pad -> o0(0,0)
#endif
}

__device__ __forceinline__ ushort f2bf(float f) {  // f32 -> bf16 RNE
  u32 u = __float_as_uint(f);
  u32 r = u + 0x7FFFu + ((u >> 16) & 1u);
  return (ushort)(r >> 16);
}

// ================= conversion / packing kernels =================
__global__ __launch_bounds__(256) void cvt_k(const float4* __restrict__ x, uint2* __restrict__ y, int n4) {
  for (int i = blockIdx.x * 256 + threadIdx.x; i < n4; i += gridDim.x * 256) {
    float4 v = x[i];
    uint2 o;
    o.x = (u32)f2bf(v.x) | ((u32)f2bf(v.y) << 16);
    o.y = (u32)f2bf(v.z) | ((u32)f2bf(v.w) << 16);
    y[i] = o;
  }
}

// pack B[K][Nn] f32 row-major -> bf16 [(k>>3)*Nn + n]*8 + (k&7)
__global__ __launch_bounds__(256) void packb_k(const float* __restrict__ B, uint4* __restrict__ out, int K, int Nn) {
  const int idx = blockIdx.x * 256 + threadIdx.x;
  const int total = (K >> 3) * Nn;
  if (idx >= total) return;
  const int g = idx / Nn;
  const int n = idx - g * Nn;
  u32 wv[4];
#pragma unroll
  for (int j = 0; j < 4; j++) {
    const float f0 = B[(size_t)(g * 8 + 2 * j) * Nn + n];
    const float f1 = B[(size_t)(g * 8 + 2 * j + 1) * Nn + n];
    wv[j] = (u32)f2bf(f0) | ((u32)f2bf(f1) << 16);
  }
  uint4 o; o.x = wv[0]; o.y = wv[1]; o.z = wv[2]; o.w = wv[3];
  out[idx] = o;
}

// ================= min/max reduction =================
__global__ __launch_bounds__(256) void minmax1_k(const float4* __restrict__ x, int n4, float* __restrict__ part, int G) {
  __shared__ float slo[256], shi[256];
  const int tid = threadIdx.x;
  float lo = 3.4e38f, hi = -3.4e38f;
  for (int i = blockIdx.x * 256 + tid; i < n4; i += G * 256) {
    float4 v = x[i];
    lo = fminf(lo, fminf(fminf(v.x, v.y), fminf(v.z, v.w)));
    hi = fmaxf(hi, fmaxf(fmaxf(v.x, v.y), fmaxf(v.z, v.w)));
  }
  slo[tid] = lo; shi[tid] = hi; __syncthreads();
  for (int s = 128; s > 0; s >>= 1) {
    if (tid < s) { slo[tid] = fminf(slo[tid], slo[tid + s]); shi[tid] = fmaxf(shi[tid], shi[tid + s]); }
    __syncthreads();
  }
  if (tid == 0) { part[blockIdx.x] = slo[0]; part[G + blockIdx.x] = shi[0]; }
}

__global__ __launch_bounds__(256) void minmax2_k(const float* __restrict__ part, int G, float* __restrict__ bnd) {
  __shared__ float slo[256], shi[256];
  const int tid = threadIdx.x;
  float lo = 3.4e38f, hi = -3.4e38f;
  for (int i = tid; i < G; i += 256) { lo = fminf(lo, part[i]); hi = fmaxf(hi, part[G + i]); }
  slo[tid] = lo; shi[tid] = hi; __syncthreads();
  for (int s = 128; s > 0; s >>= 1) {
    if (tid < s) { slo[tid] = fminf(slo[tid], slo[tid + s]); shi[tid] = fmaxf(shi[tid], shi[tid + s]); }
    __syncthreads();
  }
  if (tid == 0) { bnd[0] = slo[0]; bnd[1] = shi[0]; }
}

// ================= bf16 MFMA GEMM (m97 structure) =================
__device__ __forceinline__ void gld_lds16(const void* g, void* l) {
  __builtin_amdgcn_global_load_lds((const __attribute__((address_space(1))) void*)g,
                                   (__attribute__((address_space(3))) void*)l, 16, 0, 0);
}

// C[m][n] = epi( sum_k A[m][k]*Bp[k][n] ),  A bf16 row-major [M][K], Bp packed bf16
// EPI 1: C = (1-alpha)*acc + alpha*aux   (support)
// EPI 2: C = theta*acc + (1-theta)*aux   (final), theta = log(lamda/l + 1)
template <int EPI>
__global__ __launch_bounds__(256) void gemm_k(
    const bf16t* __restrict__ A, const bf16t* __restrict__ Bp,
    const float* __restrict__ aux, const float* __restrict__ sF,
    const int* __restrict__ sI, float* __restrict__ C, int Nn, int K) {
  __shared__ __align__(16) bf16t As[128 * 32];
  __shared__ __align__(16) bf16t Bs[128 * 32];
  const int tid = threadIdx.x;
  const int lane = tid & 63;
  const int wave = tid >> 6;
  const int nb = Nn >> 7;
  const int bm = blockIdx.x / nb;
  const int bn = blockIdx.x - bm * nb;
  const int m0 = bm << 7, n0 = bn << 7;
  const int wm = (wave & 1) << 6, wn = (wave >> 1) << 6;

  f32x4 acc[4][4];
#pragma unroll
  for (int i = 0; i < 4; i++)
#pragma unroll
    for (int j = 0; j < 4; j++) acc[i][j] = (f32x4){0.f, 0.f, 0.f, 0.f};

  const int uA0 = tid, uA1 = tid + 256;
  const bf16t* gA0 = A + (size_t)(m0 + (uA0 >> 2)) * K + ((uA0 & 3) << 3);
  const bf16t* gA1 = A + (size_t)(m0 + (uA1 >> 2)) * K + ((uA1 & 3) << 3);
  bf16t* lA0 = As + (uA0 << 3);
  bf16t* lA1 = As + (uA1 << 3);
  const bf16t* gB0 = Bp + ((size_t)(uA0 >> 7) * Nn + n0 + (uA0 & 127)) * 8;
  const bf16t* gB1 = Bp + ((size_t)(uA1 >> 7) * Nn + n0 + (uA1 & 127)) * 8;
  bf16t* lB0 = Bs + (uA0 << 3);
  bf16t* lB1 = Bs + (uA1 << 3);
  const size_t bstep = (size_t)Nn * 32;

  for (int k0 = 0; k0 < K; k0 += 32) {
    __syncthreads();
    gld_lds16(gA0 + k0, lA0);
    gld_lds16(gA1 + k0, lA1);
    gld_lds16(gB0, lB0);
    gld_lds16(gB1, lB1);
    gB0 += bstep; gB1 += bstep;
    __syncthreads();
    const int arow = lane & 15, aq = lane >> 4;
    short8 af[4], bfv[4];
#pragma unroll
    for (int mt = 0; mt < 4; mt++)
      af[mt] = *(const short8*)(As + ((wm + mt * 16 + arow) << 5) + (aq << 3));
#pragma unroll
    for (int nt = 0; nt < 4; nt++)
      bfv[nt] = *(const short8*)(Bs + (((aq << 7) + wn + nt * 16 + arow) << 3));
#pragma unroll
    for (int mt = 0; mt < 4; mt++)
#pragma unroll
      for (int nt = 0; nt < 4; nt++)
        acc[mt][nt] = __builtin_amdgcn_mfma_f32_16x16x32_bf16(af[mt], bfv[nt], acc[mt][nt], 0, 0, 0);
  }

  float p1, p2;
  if (EPI == 1) { const float al = sF[0]; p1 = 1.0f - al; p2 = al; }
  else { const float th = logf(sF[0] / (float)sI[0] + 1.0f); p1 = th; p2 = 1.0f - th; }
  const int col = lane & 15, rq = lane >> 4;
#pragma unroll
  for (int mt = 0; mt < 4; mt++)
#pragma unroll
    for (int nt = 0; nt < 4; nt++)
#pragma unroll
      for (int r = 0; r < 4; r++) {
        const int gm = m0 + wm + mt * 16 + (rq << 2) + r;
        const int gn = n0 + wn + nt * 16 + col;
        const size_t ix = (size_t)gm * Nn + gn;
        C[ix] = p1 * acc[mt][nt][r] + p2 * aux[ix];
      }
}

// ================= whale optimizer step =================
struct WA {
  u32 k1a, k1b, k2a, k2b, k3a, k3b, k4a, k4b, k5a, k5b;
  int ldr;
  float a, a2;
};

__global__ __launch_bounds__(256) void whale_k(
    const float* __restrict__ pinb, float* __restrict__ poutb,
    ushort* __restrict__ opt, const float* __restrict__ bnd, WA w) {
  const int row = blockIdx.x;
  const int tid = threadIdx.x;
  __shared__ float sh[4];
  if (tid < 4) {
    u32 ka, kb;
    if (tid == 0)      { ka = w.k1a; kb = w.k1b; }
    else if (tid == 1) { ka = w.k2a; kb = w.k2b; }
    else if (tid == 2) { ka = w.k3a; kb = w.k3b; }
    else               { ka = w.k4a; kb = w.k4b; }
    sh[tid] = unif_row(ka, kb, row);
  }
  __syncthreads();
  const float r1 = sh[0], r2 = sh[1], u3 = sh[2], p = sh[3];
  // A must match XLA's mul-then-sub bit-exactly (feeds |A|>=1): block fma contraction
  float t2 = (2.0f * w.a) * r1;
  asm volatile("" : "+v"(t2));
  const float A = t2 - w.a;
  const float Cc = 2.0f * r2;
  const float lo = bnd[0], hi = bnd[1];
  const float* pin = pinb + ((size_t)row << 10);
  const int j0 = tid << 2;
  float4 pv = *(const float4*)(pin + j0);
  float ov[4];
  const bool bp = (p < 0.5f);
  if (bp && (fabsf(A) >= 1.0f)) {  // explore: per-element random leader gather
    const u32 fb = ((u32)row << 10) + (u32)j0;
#pragma unroll
    for (int e = 0; e < 4; e++) {
      const float pos = (&pv.x)[e];
      const int ri = ridx_fn(w.k5a, w.k5b, fb + (u32)e);
      const float xr = pinb[((size_t)ri << 10) + j0 + e];
      ov[e] = fabsf(xr - A * fabsf(Cc * xr - pos));
    }
  } else {
    const float* ldp = pinb + ((size_t)w.ldr << 10);
    float4 lv = *(const float4*)(ldp + j0);
    if (bp) {  // exploit
#pragma unroll
      for (int e = 0; e < 4; e++) {
        const float pos = (&pv.x)[e], ld = (&lv.x)[e];
        ov[e] = fabsf(ld - A * fabsf(Cc * ld - pos));
      }
    } else {  // spiral
      const float lp = (w.a2 - 1.0f) * u3 + 1.0f;
      const float s1 = expf(lp);
      const float s2 = cosf(6.2831855f * lp);
#pragma unroll
      for (int e = 0; e < 4; e++) {
        const float pos = (&pv.x)[e], ld = (&lv.x)[e];
        ov[e] = fabsf(fabsf(ld - pos) * s1 * s2 + ld);
      }
    }
  }
  float4 res;
#pragma unroll
  for (int e = 0; e < 4; e++) (&res.x)[e] = fminf(fmaxf(ov[e], lo), hi);
  *(float4*)(poutb + ((size_t)row << 10) + j0) = res;
  if (opt) {
    ushort4 o4;
    o4.x = f2bf(res.x); o4.y = f2bf(res.y); o4.z = f2bf(res.z); o4.w = f2bf(res.w);
    *(ushort4*)(opt + ((size_t)row << 10) + j0) = o4;
  }
}

// ================= host =================
extern "C" void kernel_launch(void* const* d_in, const int* in_sizes, int n_in,
                              void* d_out, int out_size, void* d_ws, size_t ws_size,
                              hipStream_t stream) {
  const float* inp = (const float*)d_in[0];   // input  [8192,1024]
  const float* adj = (const float*)d_in[1];   // adj    [8192,8192]
  const float* h0  = (const float*)d_in[2];   // h0     [8192,1024]
  const float* wgt = (const float*)d_in[3];   // weight [1024,1024]
  const float* lam = (const float*)d_in[4];   // lamda scalar
  const float* alp = (const float*)d_in[5];   // alpha scalar
  const int* lint  = (const int*)d_in[6];     // l scalar
  float* outp = (float*)d_out;

  char* ws = (char*)d_ws;
  // adj_bf16 region [0,134.2MB) is dead after gemm1; whale buffers overlay it.
  bf16t* Abf  = (bf16t*)(ws);
  float* P0   = (float*)(ws);
  float* P1   = (float*)(ws + 33554432);
  ushort* OPT = (ushort*)(ws + 67108864);
  bf16t* B1p  = (bf16t*)(ws + 134217728);   // 16.8MB
  bf16t* Wp   = (bf16t*)(ws + 150994944);   // 2.1MB
  float* SUP  = (float*)(ws + 153092096);   // 33.6MB (support, live to the end)
  float* PRT  = (float*)(ws + 186646528);   // 16KB partials
  float* BND  = (float*)(ws + 186662912);   // lower/upper

  // 1) adj f32 -> bf16
  hipLaunchKernelGGL(cvt_k, dim3(4096), dim3(256), 0, stream, (const float4*)adj, (uint2*)Abf, 16777216);
  // 2) pack input, weight into MFMA-friendly bf16 layout
  hipLaunchKernelGGL(packb_k, dim3(4096), dim3(256), 0, stream, inp, (uint4*)B1p, 8192, 1024);
  hipLaunchKernelGGL(packb_k, dim3(512), dim3(256), 0, stream, wgt, (uint4*)Wp, 1024, 1024);
  // 3) support = (1-alpha)*(adj@input) + alpha*h0
  hipLaunchKernelGGL((gemm_k<1>), dim3(512), dim3(256), 0, stream, Abf, B1p, h0, alp, lint, SUP, 1024, 8192);
  // 4) lower/upper = min/max(support)
  hipLaunchKernelGGL(minmax1_k, dim3(2048), dim3(256), 0, stream, (const float4*)SUP, 2097152, PRT, 2048);
  hipLaunchKernelGGL(minmax2_k, dim3(1), dim3(256), 0, stream, PRT, 2048, BND);

  // 5) whale optimizer: key(42) = (0,42); split -> (k0, loop_key)
  u32 k0k[2], lpk[2];
  split2(0u, 42u, k0k, lpk);
  int ldr = scalar_randint8192(k0k[0], k0k[1]);
  const float* cur = SUP;
  float* bufs[2] = {P0, P1};
  for (int it = 0; it < 10; ++it) {
    u32 ka, kb; tf2(lpk[0], lpk[1], 0u, (u32)it, ka, kb);  // fold_in(loop_key, it)
    u32 ks[6][2];
    split6(ka, kb, ks);
    // randint key k5 pre-split: use split(k5)[1]
    u32 k5A[2], k5B[2];
    split2(ks[4][0], ks[4][1], k5A, k5B);
    WA w;
    w.k1a = ks[0][0]; w.k1b = ks[0][1];
    w.k2a = ks[1][0]; w.k2b = ks[1][1];
    w.k3a = ks[2][0]; w.k3b = ks[2][1];
    w.k4a = ks[3][0]; w.k4b = ks[3][1];
    w.k5a = k5B[0];   w.k5b = k5B[1];
    w.ldr = ldr;
    const float itf = (float)it;
    w.a = 2.0f - itf * 0.2f;
    w.a2 = -1.0f + itf * (-0.1f);
    float* nxt = bufs[it & 1];
    hipLaunchKernelGGL(whale_k, dim3(8192), dim3(256), 0, stream, cur, nxt,
                       (it == 9) ? OPT : (ushort*)nullptr, BND, w);
    cur = nxt;
    ldr = scalar_randint8192(ks[5][0], ks[5][1]);  // leader index for next iter
  }
  // 6) out = theta*(opt@weight) + (1-theta)*support
  hipLaunchKernelGGL((gemm_k<2>), dim3(512), dim3(256), 0, stream, (const bf16t*)OPT, Wp, SUP, lam, lint, outp, 1024, 1024);
  (void)in_sizes; (void)n_in; (void)out_size; (void)ws_size;
}

// Round 3
// 907.497 us; speedup vs baseline: 1.0541x; 1.0541x over previous
//
#include <hip/hip_runtime.h>
#include <hip/hip_bf16.h>
#include <stdint.h>
#include <math.h>

typedef uint32_t u32;
typedef __hip_bfloat16 bf16t;
typedef __attribute__((ext_vector_type(8))) short short8;
typedef __attribute__((ext_vector_type(4))) float f32x4;

// JAX PRNG: threefry2x32, jax_threefry_partitionable=True semantics (verified R2):
//   split(key,n)[i] = (o0(key;0,i), o1(key;0,i))
//   random_bits32(key,shape)[f] = o0(key;0,f) ^ o1(key;0,f)
//   randint pre-splits its key, uses subkey2; span 8192 pow2 -> bits & 8191
//   fold_in(key,d) = threefry(key,(0,d))

// ================= threefry2x32 (bit-exact vs JAX) =================
__host__ __device__ __forceinline__ void tf2(u32 k0, u32 k1, u32 c0, u32 c1, u32& o0, u32& o1) {
  const u32 ks2 = k0 ^ k1 ^ 0x1BD11BDAu;
  u32 x0 = c0 + k0, x1 = c1 + k1;
#define TFROT(v,r) (((v)<<(r))|((v)>>(32-(r))))
#define TFR(r) { x0 += x1; x1 = TFROT(x1,r); x1 ^= x0; }
  TFR(13) TFR(15) TFR(26) TFR(6)   x0 += k1;  x1 += ks2 + 1u;
  TFR(17) TFR(29) TFR(16) TFR(24)  x0 += ks2; x1 += k0 + 2u;
  TFR(13) TFR(15) TFR(26) TFR(6)   x0 += k0;  x1 += k1 + 3u;
  TFR(17) TFR(29) TFR(16) TFR(24)  x0 += k1;  x1 += ks2 + 4u;
  TFR(13) TFR(15) TFR(26) TFR(6)   x0 += ks2; x1 += k0 + 5u;
#undef TFR
#undef TFROT
  o0 = x0; o1 = x1;
}

__device__ __forceinline__ float unif_row(u32 ka, u32 kb, int i) {
  u32 o0, o1;
  tf2(ka, kb, 0u, (u32)i, o0, o1);
  return __uint_as_float(0x3F800000u | ((o0 ^ o1) >> 9)) - 1.0f;
}

__device__ __forceinline__ int ridx_fn(u32 ka, u32 kb, u32 f) {
  u32 o0, o1; tf2(ka, kb, 0u, f, o0, o1); return (int)((o0 ^ o1) & 8191u);
}

static inline void split2(u32 ka, u32 kb, u32* kA, u32* kB) {
  u32 a0, a1, b0, b1;
  tf2(ka, kb, 0u, 0u, a0, a1);
  tf2(ka, kb, 0u, 1u, b0, b1);
  kA[0] = a0; kA[1] = a1; kB[0] = b0; kB[1] = b1;
}

static inline void split6(u32 ka, u32 kb, u32 out[6][2]) {
  for (u32 i = 0; i < 6; i++) { u32 o0, o1; tf2(ka, kb, 0u, i, o0, o1); out[i][0] = o0; out[i][1] = o1; }
}

static inline int scalar_randint8192(u32 ka, u32 kb) {
  u32 kA[2], kB[2];
  split2(ka, kb, kA, kB);
  u32 o0, o1;
  tf2(kB[0], kB[1], 0u, 0u, o0, o1);
  return (int)((o0 ^ o1) & 8191u);
}

__device__ __forceinline__ ushort f2bf(float f) {  // f32 -> bf16 RNE
  u32 u = __float_as_uint(f);
  u32 r = u + 0x7FFFu + ((u >> 16) & 1u);
  return (ushort)(r >> 16);
}

// ================= conversion / packing kernels =================
__global__ __launch_bounds__(256) void cvt_k(const float4* __restrict__ x, uint2* __restrict__ y, int n4) {
  for (int i = blockIdx.x * 256 + threadIdx.x; i < n4; i += gridDim.x * 256) {
    float4 v = x[i];
    uint2 o;
    o.x = (u32)f2bf(v.x) | ((u32)f2bf(v.y) << 16);
    o.y = (u32)f2bf(v.z) | ((u32)f2bf(v.w) << 16);
    y[i] = o;
  }
}

// pack B[K][Nn] f32 row-major -> bf16 [(k>>3)*Nn + n]*8 + (k&7)
__global__ __launch_bounds__(256) void packb_k(const float* __restrict__ B, uint4* __restrict__ out, int K, int Nn) {
  const int idx = blockIdx.x * 256 + threadIdx.x;
  const int total = (K >> 3) * Nn;
  if (idx >= total) return;
  const int g = idx / Nn;
  const int n = idx - g * Nn;
  u32 wv[4];
#pragma unroll
  for (int j = 0; j < 4; j++) {
    const float f0 = B[(size_t)(g * 8 + 2 * j) * Nn + n];
    const float f1 = B[(size_t)(g * 8 + 2 * j + 1) * Nn + n];
    wv[j] = (u32)f2bf(f0) | ((u32)f2bf(f1) << 16);
  }
  uint4 o; o.x = wv[0]; o.y = wv[1]; o.z = wv[2]; o.w = wv[3];
  out[idx] = o;
}

__global__ __launch_bounds__(256) void minmax2_k(const float* __restrict__ part, int G, float* __restrict__ bnd) {
  __shared__ float slo[256], shi[256];
  const int tid = threadIdx.x;
  float lo = 3.4e38f, hi = -3.4e38f;
  for (int i = tid; i < G; i += 256) { lo = fminf(lo, part[i]); hi = fmaxf(hi, part[G + i]); }
  slo[tid] = lo; shi[tid] = hi; __syncthreads();
  for (int s = 128; s > 0; s >>= 1) {
    if (tid < s) { slo[tid] = fminf(slo[tid], slo[tid + s]); shi[tid] = fmaxf(shi[tid], shi[tid + s]); }
    __syncthreads();
  }
  if (tid == 0) { bnd[0] = slo[0]; bnd[1] = shi[0]; }
}

// ================= bf16 MFMA GEMM — 512-thread, 8-wave, XCD-swizzled =================
__device__ __forceinline__ void gld_lds16(const void* g, void* l) {
  __builtin_amdgcn_global_load_lds((const __attribute__((address_space(1))) void*)g,
                                   (__attribute__((address_space(3))) void*)l, 16, 0, 0);
}

// C[m][n] = epi( sum_k A[m][k]*Bp[k][n] ),  A bf16 row-major [M][K], Bp packed bf16.
// Grid: 64 m-blocks x 8 n-blocks; bm = blockIdx&63 so XCD = bm&7 (all n-blocks of
// an A-panel share one XCD's L2 -> A fetched ~once from HBM).
// EPI 1: C = (1-alpha)*acc + alpha*aux, + block min/max -> prt (support)
// EPI 2: C = theta*acc + (1-theta)*aux, theta = log(lamda/l + 1)   (final)
template <int EPI>
__global__ __launch_bounds__(512, 4) void gemm_k(
    const bf16t* __restrict__ A, const bf16t* __restrict__ Bp,
    const float* __restrict__ aux, const float* __restrict__ sF,
    const int* __restrict__ sI, float* __restrict__ C,
    float* __restrict__ prt, int PG, int Nn, int K) {
  __shared__ __align__(16) bf16t As[128 * 32];
  __shared__ __align__(16) bf16t Bs[128 * 32];
  const int tid = threadIdx.x;
  const int lane = tid & 63;
  const int wave = tid >> 6;                 // 0..7
  const int bm = blockIdx.x & 63;
  const int bn = blockIdx.x >> 6;
  const int m0 = bm << 7, n0 = bn << 7;
  const int wm = (wave & 1) << 6;            // 0,64
  const int wn = (wave >> 1) << 5;           // 0,32,64,96

  f32x4 acc[4][2];
#pragma unroll
  for (int i = 0; i < 4; i++)
#pragma unroll
    for (int j = 0; j < 2; j++) acc[i][j] = (f32x4){0.f, 0.f, 0.f, 0.f};

  const bf16t* gA = A + (size_t)(m0 + (tid >> 2)) * K + ((tid & 3) << 3);
  bf16t* lA = As + (tid << 3);
  const bf16t* gB = Bp + ((size_t)(tid >> 7) * Nn + n0 + (tid & 127)) * 8;
  bf16t* lB = Bs + (tid << 3);
  const size_t bstep = (size_t)Nn * 32;      // 4 k-groups per K-step

  for (int k0 = 0; k0 < K; k0 += 32) {
    __syncthreads();
    gld_lds16(gA + k0, lA);
    gld_lds16(gB, lB);
    gB += bstep;
    __syncthreads();
    const int arow = lane & 15, aq = lane >> 4;
    short8 af[4], bfv[2];
#pragma unroll
    for (int mt = 0; mt < 4; mt++)
      af[mt] = *(const short8*)(As + ((wm + mt * 16 + arow) << 5) + (aq << 3));
#pragma unroll
    for (int nt = 0; nt < 2; nt++)
      bfv[nt] = *(const short8*)(Bs + (((aq << 7) + wn + nt * 16 + arow) << 3));
#pragma unroll
    for (int mt = 0; mt < 4; mt++)
#pragma unroll
      for (int nt = 0; nt < 2; nt++)
        acc[mt][nt] = __builtin_amdgcn_mfma_f32_16x16x32_bf16(af[mt], bfv[nt], acc[mt][nt], 0, 0, 0);
  }

  float p1, p2;
  if (EPI == 1) { const float al = sF[0]; p1 = 1.0f - al; p2 = al; }
  else { const float th = logf(sF[0] / (float)sI[0] + 1.0f); p1 = th; p2 = 1.0f - th; }
  const int col = lane & 15, rq = lane >> 4;
  float vlo = 3.4e38f, vhi = -3.4e38f;
#pragma unroll
  for (int mt = 0; mt < 4; mt++)
#pragma unroll
    for (int nt = 0; nt < 2; nt++)
#pragma unroll
      for (int r = 0; r < 4; r++) {
        const int gm = m0 + wm + mt * 16 + (rq << 2) + r;
        const int gn = n0 + wn + nt * 16 + col;
        const size_t ix = (size_t)gm * Nn + gn;
        const float v = p1 * acc[mt][nt][r] + p2 * aux[ix];
        C[ix] = v;
        if (EPI == 1) { vlo = fminf(vlo, v); vhi = fmaxf(vhi, v); }
      }
  if (EPI == 1) {  // fused block min/max -> partials
    __syncthreads();  // As no longer needed for MFMA
    float* red = (float*)As;  // 512 lo + 512 hi  (4 KB of the 8 KB As)
    red[tid] = vlo; red[512 + tid] = vhi;
    __syncthreads();
    for (int s = 256; s > 0; s >>= 1) {
      if (tid < s) {
        red[tid] = fminf(red[tid], red[tid + s]);
        red[512 + tid] = fmaxf(red[512 + tid], red[512 + tid + s]);
      }
      __syncthreads();
    }
    if (tid == 0) { prt[blockIdx.x] = red[0]; prt[PG + blockIdx.x] = red[512]; }
  }
}

// ================= whale optimizer step =================
struct WA {
  u32 k1a, k1b, k2a, k2b, k3a, k3b, k4a, k4b, k5a, k5b;
  int ldr;
  float a, a2;
};

__global__ __launch_bounds__(256) void whale_k(
    const float* __restrict__ pinb, float* __restrict__ poutb,
    ushort* __restrict__ opt, const float* __restrict__ bnd, WA w) {
  const int row = blockIdx.x;
  const int tid = threadIdx.x;
  __shared__ float sh[4];
  if (tid < 4) {
    u32 ka, kb;
    if (tid == 0)      { ka = w.k1a; kb = w.k1b; }
    else if (tid == 1) { ka = w.k2a; kb = w.k2b; }
    else if (tid == 2) { ka = w.k3a; kb = w.k3b; }
    else               { ka = w.k4a; kb = w.k4b; }
    sh[tid] = unif_row(ka, kb, row);
  }
  __syncthreads();
  const float r1 = sh[0], r2 = sh[1], u3 = sh[2], p = sh[3];
  // A feeds the |A|>=1 branch decision: match XLA's mul-then-sub (no fma contraction)
  float t2 = (2.0f * w.a) * r1;
  asm volatile("" : "+v"(t2));
  const float A = t2 - w.a;
  const float Cc = 2.0f * r2;
  const float lo = bnd[0], hi = bnd[1];
  const float* pin = pinb + ((size_t)row << 10);
  const int j0 = tid << 2;
  float4 pv = *(const float4*)(pin + j0);
  float ov[4];
  const bool bp = (p < 0.5f);
  if (bp && (fabsf(A) >= 1.0f)) {  // explore: per-element random-row gather
    const u32 fb = ((u32)row << 10) + (u32)j0;
#pragma unroll
    for (int e = 0; e < 4; e++) {
      const float pos = (&pv.x)[e];
      const int ri = ridx_fn(w.k5a, w.k5b, fb + (u32)e);
      const float xr = pinb[((size_t)ri << 10) + j0 + e];
      ov[e] = fabsf(xr - A * fabsf(Cc * xr - pos));
    }
  } else {
    const float* ldp = pinb + ((size_t)w.ldr << 10);
    float4 lv = *(const float4*)(ldp + j0);
    if (bp) {  // exploit
#pragma unroll
      for (int e = 0; e < 4; e++) {
        const float pos = (&pv.x)[e], ld = (&lv.x)[e];
        ov[e] = fabsf(ld - A * fabsf(Cc * ld - pos));
      }
    } else {  // spiral
      const float lp = (w.a2 - 1.0f) * u3 + 1.0f;
      const float s1 = expf(lp);
      const float s2 = cosf(6.2831855f * lp);
#pragma unroll
      for (int e = 0; e < 4; e++) {
        const float pos = (&pv.x)[e], ld = (&lv.x)[e];
        ov[e] = fabsf(fabsf(ld - pos) * s1 * s2 + ld);
      }
    }
  }
  float4 res;
#pragma unroll
  for (int e = 0; e < 4; e++) (&res.x)[e] = fminf(fmaxf(ov[e], lo), hi);
  *(float4*)(poutb + ((size_t)row << 10) + j0) = res;
  if (opt) {
    ushort4 o4;
    o4.x = f2bf(res.x); o4.y = f2bf(res.y); o4.z = f2bf(res.z); o4.w = f2bf(res.w);
    *(ushort4*)(opt + ((size_t)row << 10) + j0) = o4;
  }
}

// ================= host =================
extern "C" void kernel_launch(void* const* d_in, const int* in_sizes, int n_in,
                              void* d_out, int out_size, void* d_ws, size_t ws_size,
                              hipStream_t stream) {
  const float* inp = (const float*)d_in[0];   // input  [8192,1024]
  const float* adj = (const float*)d_in[1];   // adj    [8192,8192]
  const float* h0  = (const float*)d_in[2];   // h0     [8192,1024]
  const float* wgt = (const float*)d_in[3];   // weight [1024,1024]
  const float* lam = (const float*)d_in[4];   // lamda scalar
  const float* alp = (const float*)d_in[5];   // alpha scalar
  const int* lint  = (const int*)d_in[6];     // l scalar
  float* outp = (float*)d_out;

  char* ws = (char*)d_ws;
  // adj_bf16 region [0,134.2MB) is dead after gemm1; whale buffers overlay it.
  bf16t* Abf  = (bf16t*)(ws);
  float* P0   = (float*)(ws);
  float* P1   = (float*)(ws + 33554432);
  ushort* OPT = (ushort*)(ws + 67108864);
  bf16t* B1p  = (bf16t*)(ws + 134217728);   // 16.8MB
  bf16t* Wp   = (bf16t*)(ws + 150994944);   // 2.1MB
  float* SUP  = (float*)(ws + 153092096);   // 33.6MB (support, live to the end)
  float* PRT  = (float*)(ws + 186646528);   // 4KB partials (512 lo + 512 hi)
  float* BND  = (float*)(ws + 186662912);   // lower/upper

  // 1) adj f32 -> bf16
  hipLaunchKernelGGL(cvt_k, dim3(4096), dim3(256), 0, stream, (const float4*)adj, (uint2*)Abf, 16777216);
  // 2) pack input, weight into MFMA-friendly bf16 layout
  hipLaunchKernelGGL(packb_k, dim3(4096), dim3(256), 0, stream, inp, (uint4*)B1p, 8192, 1024);
  hipLaunchKernelGGL(packb_k, dim3(512), dim3(256), 0, stream, wgt, (uint4*)Wp, 1024, 1024);
  // 3) support = (1-alpha)*(adj@input) + alpha*h0   (+ fused block min/max)
  hipLaunchKernelGGL((gemm_k<1>), dim3(512), dim3(512), 0, stream, Abf, B1p, h0, alp, lint, SUP, PRT, 512, 1024, 8192);
  // 4) reduce 512 block partials -> lower/upper
  hipLaunchKernelGGL(minmax2_k, dim3(1), dim3(256), 0, stream, PRT, 512, BND);

  // 5) whale optimizer: key(42) = (0,42); split -> (k0, loop_key)
  u32 k0k[2], lpk[2];
  split2(0u, 42u, k0k, lpk);
  int ldr = scalar_randint8192(k0k[0], k0k[1]);
  const float* cur = SUP;
  float* bufs[2] = {P0, P1};
  for (int it = 0; it < 10; ++it) {
    u32 ka, kb; tf2(lpk[0], lpk[1], 0u, (u32)it, ka, kb);  // fold_in(loop_key, it)
    u32 ks[6][2];
    split6(ka, kb, ks);
    u32 k5A[2], k5B[2];
    split2(ks[4][0], ks[4][1], k5A, k5B);  // randint pre-split: use subkey2
    WA w;
    w.k1a = ks[0][0]; w.k1b = ks[0][1];
    w.k2a = ks[1][0]; w.k2b = ks[1][1];
    w.k3a = ks[2][0]; w.k3b = ks[2][1];
    w.k4a = ks[3][0]; w.k4b = ks[3][1];
    w.k5a = k5B[0];   w.k5b = k5B[1];
    w.ldr = ldr;
    const float itf = (float)it;
    w.a = 2.0f - itf * 0.2f;
    w.a2 = -1.0f + itf * (-0.1f);
    float* nxt = bufs[it & 1];
    hipLaunchKernelGGL(whale_k, dim3(8192), dim3(256), 0, stream, cur, nxt,
                       (it == 9) ? OPT : (ushort*)nullptr, BND, w);
    cur = nxt;
    ldr = scalar_randint8192(ks[5][0], ks[5][1]);  // leader index for next iter
  }
  // 6) out = theta*(opt@weight) + (1-theta)*support
  hipLaunchKernelGGL((gemm_k<2>), dim3(512), dim3(512), 0, stream, (const bf16t*)OPT, Wp, SUP, lam, lint, outp,
                     (float*)nullptr, 0, 1024, 1024);
  (void)in_sizes; (void)n_in; (void)out_size; (void)ws_size;
}

// Round 4
// 862.901 us; speedup vs baseline: 1.1086x; 1.0517x over previous
//
#include <hip/hip_runtime.h>
#include <hip/hip_bf16.h>
#include <stdint.h>
#include <math.h>

typedef uint32_t u32;
typedef __hip_bfloat16 bf16t;
typedef __attribute__((ext_vector_type(8))) short short8;
typedef __attribute__((ext_vector_type(4))) float f32x4;

// JAX PRNG: threefry2x32, jax_threefry_partitionable=True semantics (verified R2):
//   split(key,n)[i] = (o0(key;0,i), o1(key;0,i))
//   random_bits32(key,shape)[f] = o0(key;0,f) ^ o1(key;0,f)
//   randint pre-splits its key, uses subkey2; span 8192 pow2 -> bits & 8191
//   fold_in(key,d) = threefry(key,(0,d))

// ================= threefry2x32 (bit-exact vs JAX) =================
__host__ __device__ __forceinline__ void tf2(u32 k0, u32 k1, u32 c0, u32 c1, u32& o0, u32& o1) {
  const u32 ks2 = k0 ^ k1 ^ 0x1BD11BDAu;
  u32 x0 = c0 + k0, x1 = c1 + k1;
#define TFROT(v,r) (((v)<<(r))|((v)>>(32-(r))))
#define TFR(r) { x0 += x1; x1 = TFROT(x1,r); x1 ^= x0; }
  TFR(13) TFR(15) TFR(26) TFR(6)   x0 += k1;  x1 += ks2 + 1u;
  TFR(17) TFR(29) TFR(16) TFR(24)  x0 += ks2; x1 += k0 + 2u;
  TFR(13) TFR(15) TFR(26) TFR(6)   x0 += k0;  x1 += k1 + 3u;
  TFR(17) TFR(29) TFR(16) TFR(24)  x0 += k1;  x1 += ks2 + 4u;
  TFR(13) TFR(15) TFR(26) TFR(6)   x0 += ks2; x1 += k0 + 5u;
#undef TFR
#undef TFROT
  o0 = x0; o1 = x1;
}

__device__ __forceinline__ float unif_row(u32 ka, u32 kb, int i) {
  u32 o0, o1;
  tf2(ka, kb, 0u, (u32)i, o0, o1);
  return __uint_as_float(0x3F800000u | ((o0 ^ o1) >> 9)) - 1.0f;
}

__device__ __forceinline__ int ridx_fn(u32 ka, u32 kb, u32 f) {
  u32 o0, o1; tf2(ka, kb, 0u, f, o0, o1); return (int)((o0 ^ o1) & 8191u);
}

static inline void split2(u32 ka, u32 kb, u32* kA, u32* kB) {
  u32 a0, a1, b0, b1;
  tf2(ka, kb, 0u, 0u, a0, a1);
  tf2(ka, kb, 0u, 1u, b0, b1);
  kA[0] = a0; kA[1] = a1; kB[0] = b0; kB[1] = b1;
}

static inline void split6(u32 ka, u32 kb, u32 out[6][2]) {
  for (u32 i = 0; i < 6; i++) { u32 o0, o1; tf2(ka, kb, 0u, i, o0, o1); out[i][0] = o0; out[i][1] = o1; }
}

static inline int scalar_randint8192(u32 ka, u32 kb) {
  u32 kA[2], kB[2];
  split2(ka, kb, kA, kB);
  u32 o0, o1;
  tf2(kB[0], kB[1], 0u, 0u, o0, o1);
  return (int)((o0 ^ o1) & 8191u);
}

__device__ __forceinline__ ushort f2bf(float f) {  // f32 -> bf16 RNE
  u32 u = __float_as_uint(f);
  u32 r = u + 0x7FFFu + ((u >> 16) & 1u);
  return (ushort)(r >> 16);
}

// ================= packing kernels =================
// pack B[K][Nn] f32 row-major -> bf16 [(k>>3)*Nn + n]*8 + (k&7)
__global__ __launch_bounds__(256) void packb_k(const float* __restrict__ B, uint4* __restrict__ out, int K, int Nn) {
  const int idx = blockIdx.x * 256 + threadIdx.x;
  const int total = (K >> 3) * Nn;
  if (idx >= total) return;
  const int g = idx / Nn;
  const int n = idx - g * Nn;
  u32 wv[4];
#pragma unroll
  for (int j = 0; j < 4; j++) {
    const float f0 = B[(size_t)(g * 8 + 2 * j) * Nn + n];
    const float f1 = B[(size_t)(g * 8 + 2 * j + 1) * Nn + n];
    wv[j] = (u32)f2bf(f0) | ((u32)f2bf(f1) << 16);
  }
  uint4 o; o.x = wv[0]; o.y = wv[1]; o.z = wv[2]; o.w = wv[3];
  out[idx] = o;
}

__global__ __launch_bounds__(256) void minmax2_k(const float* __restrict__ part, int G, float* __restrict__ bnd) {
  __shared__ float slo[256], shi[256];
  const int tid = threadIdx.x;
  float lo = 3.4e38f, hi = -3.4e38f;
  for (int i = tid; i < G; i += 256) { lo = fminf(lo, part[i]); hi = fmaxf(hi, part[G + i]); }
  slo[tid] = lo; shi[tid] = hi; __syncthreads();
  for (int s = 128; s > 0; s >>= 1) {
    if (tid < s) { slo[tid] = fminf(slo[tid], slo[tid + s]); shi[tid] = fmaxf(shi[tid], shi[tid + s]); }
    __syncthreads();
  }
  if (tid == 0) { bnd[0] = slo[0]; bnd[1] = shi[0]; }
}

// ================= bf16 MFMA GEMM — BK=64, dbuf LDS, 1 barrier/step =================
__device__ __forceinline__ void gld_lds16(const void* g, void* l) {
  __builtin_amdgcn_global_load_lds((const __attribute__((address_space(1))) void*)g,
                                   (__attribute__((address_space(3))) void*)l, 16, 0, 0);
}

// C[m][n] = epi( sum_k A[m][k]*Bp[k][n] ).
// A: AF32=1 -> f32 row-major (converted to bf16 in-kernel, staged via ds_write to
//    a +72-padded LDS layout — kills both the cvt pass and A-frag bank conflicts);
//    AF32=0 -> bf16 row-major. Bp: packed bf16 (k-group-major), staged via
//    global_load_lds (layout is lane-contiguous by construction).
// K-loop: BK=64 super-steps, double-buffered LDS, prefetch for s+1 issued right
// after the barrier so the next barrier's vmcnt(0) drain finds it complete.
// Grid: bm = blockIdx&63 (XCD = bm&7), bn = blockIdx>>6 — n-blocks of an A-panel
// share one XCD's L2 (R3: FETCH dropped to ~ideal).
// EPI 1: C = (1-alpha)*acc + alpha*aux, + fused block min/max -> prt
// EPI 2: C = theta*acc + (1-theta)*aux, theta = log(lamda/l + 1)
template <int EPI, int AF32>
__global__ __launch_bounds__(512, 4) void gemm_k(
    const void* __restrict__ Araw, const bf16t* __restrict__ Bp,
    const float* __restrict__ aux, const float* __restrict__ sF,
    const int* __restrict__ sI, float* __restrict__ C,
    float* __restrict__ prt, int PG, int Nn, int K) {
  constexpr int APAD = 72;  // A row stride in LDS (bf16): 144B = 36 banks -> 2-way max
  __shared__ __align__(16) bf16t As[2][128 * APAD];
  __shared__ __align__(16) bf16t Bs[2][128 * 64];
  const int tid = threadIdx.x;
  const int lane = tid & 63;
  const int wave = tid >> 6;                 // 0..7
  const int bm = blockIdx.x & 63;
  const int bn = blockIdx.x >> 6;
  const int m0 = bm << 7, n0 = bn << 7;
  const int wm = (wave & 1) << 6;            // 0,64
  const int wn = (wave >> 1) << 5;           // 0,32,64,96

  f32x4 acc[4][2];
#pragma unroll
  for (int i = 0; i < 4; i++)
#pragma unroll
    for (int j = 0; j < 2; j++) acc[i][j] = (f32x4){0.f, 0.f, 0.f, 0.f};

  const float* Af = (const float*)Araw;
  const bf16t* Ab = (const bf16t*)Araw;
  // staging units: u and u+512; A unit u: row u>>3, cols (u&7)*8..+8 of the 128x64 tile
  //                B unit u: k-group u>>7 (0..7), col u&127
  const int u0 = tid, u1 = tid + 512;
  const int ar0 = u0 >> 3, ac0 = (u0 & 7) << 3;
  const int ar1 = u1 >> 3, ac1 = (u1 & 7) << 3;
  const bf16t* gB0 = Bp + ((size_t)(u0 >> 7) * Nn + n0 + (u0 & 127)) * 8;
  const bf16t* gB1 = Bp + ((size_t)(u1 >> 7) * Nn + n0 + (u1 & 127)) * 8;
  const size_t bstep = (size_t)Nn * 64;      // 8 k-groups per super-step

  float4 a32[2][2];  // AF32 staging regs
  short8 a16[2];     // bf16 staging regs

  auto issueA = [&](int s) {
    if (AF32) {
      const float* p0 = Af + (size_t)(m0 + ar0) * K + (s << 6) + ac0;
      const float* p1 = Af + (size_t)(m0 + ar1) * K + (s << 6) + ac1;
      a32[0][0] = *(const float4*)p0; a32[0][1] = *(const float4*)(p0 + 4);
      a32[1][0] = *(const float4*)p1; a32[1][1] = *(const float4*)(p1 + 4);
    } else {
      a16[0] = *(const short8*)(Ab + (size_t)(m0 + ar0) * K + (s << 6) + ac0);
      a16[1] = *(const short8*)(Ab + (size_t)(m0 + ar1) * K + (s << 6) + ac1);
    }
  };
  auto writeA = [&](int buf) {
#pragma unroll
    for (int i = 0; i < 2; i++) {
      short8 v;
      if (AF32) {
#pragma unroll
        for (int e = 0; e < 4; e++) v[e] = (short)f2bf((&a32[i][0].x)[e]);
#pragma unroll
        for (int e = 0; e < 4; e++) v[4 + e] = (short)f2bf((&a32[i][1].x)[e]);
      } else {
        v = a16[i];
      }
      const int r = i ? ar1 : ar0, cc = i ? ac1 : ac0;
      *(short8*)(&As[buf][r * APAD + cc]) = v;
    }
  };
  auto stageB = [&](int s, int buf) {
    gld_lds16(gB0 + (size_t)s * bstep, &Bs[buf][u0 << 3]);
    gld_lds16(gB1 + (size_t)s * bstep, &Bs[buf][u1 << 3]);
  };

  // prologue: stage step 0 into buffer 0
  issueA(0);
  stageB(0, 0);
  writeA(0);

  const int S = K >> 6;
  const int arow = lane & 15, aq = lane >> 4;
  for (int s = 0; s < S; ++s) {
    const int cur = s & 1;
    __syncthreads();  // drains step-s prefetch (vmcnt + lgkm), publishes buf[cur]
    const bool more = (s + 1 < S);
    if (more) { stageB(s + 1, cur ^ 1); issueA(s + 1); }
#pragma unroll
    for (int c = 0; c < 2; ++c) {
      short8 af[4], bfv[2];
#pragma unroll
      for (int mt = 0; mt < 4; mt++)
        af[mt] = *(const short8*)(&As[cur][(wm + mt * 16 + arow) * APAD + (c << 5) + (aq << 3)]);
#pragma unroll
      for (int nt = 0; nt < 2; nt++)
        bfv[nt] = *(const short8*)(&Bs[cur][(((c << 2) + aq) * 128 + wn + nt * 16 + arow) << 3]);
#pragma unroll
      for (int mt = 0; mt < 4; mt++)
#pragma unroll
        for (int nt = 0; nt < 2; nt++)
          acc[mt][nt] = __builtin_amdgcn_mfma_f32_16x16x32_bf16(af[mt], bfv[nt], acc[mt][nt], 0, 0, 0);
    }
    if (more) writeA(cur ^ 1);  // waits only on the A global loads (fine-grained vmcnt)
  }

  float p1, p2;
  if (EPI == 1) { const float al = sF[0]; p1 = 1.0f - al; p2 = al; }
  else { const float th = logf(sF[0] / (float)sI[0] + 1.0f); p1 = th; p2 = 1.0f - th; }
  const int col = lane & 15, rq = lane >> 4;
  float vlo = 3.4e38f, vhi = -3.4e38f;
#pragma unroll
  for (int mt = 0; mt < 4; mt++)
#pragma unroll
    for (int nt = 0; nt < 2; nt++)
#pragma unroll
      for (int r = 0; r < 4; r++) {
        const int gm = m0 + wm + mt * 16 + (rq << 2) + r;
        const int gn = n0 + wn + nt * 16 + col;
        const size_t ix = (size_t)gm * Nn + gn;
        const float v = p1 * acc[mt][nt][r] + p2 * aux[ix];
        C[ix] = v;
        if (EPI == 1) { vlo = fminf(vlo, v); vhi = fmaxf(vhi, v); }
      }
  if (EPI == 1) {  // fused block min/max -> partials
    __syncthreads();
    float* red = (float*)&As[0][0];
    red[tid] = vlo; red[512 + tid] = vhi;
    __syncthreads();
    for (int s = 256; s > 0; s >>= 1) {
      if (tid < s) {
        red[tid] = fminf(red[tid], red[tid + s]);
        red[512 + tid] = fmaxf(red[512 + tid], red[512 + tid + s]);
      }
      __syncthreads();
    }
    if (tid == 0) { prt[blockIdx.x] = red[0]; prt[PG + blockIdx.x] = red[512]; }
  }
}

// ================= whale optimizer step =================
struct WA {
  u32 k1a, k1b, k2a, k2b, k3a, k3b, k4a, k4b, k5a, k5b;
  int ldr;
  float a, a2;
};

__global__ __launch_bounds__(256) void whale_k(
    const float* __restrict__ pinb, float* __restrict__ poutb,
    ushort* __restrict__ opt, const float* __restrict__ bnd, WA w) {
  const int row = blockIdx.x;
  const int tid = threadIdx.x;
  __shared__ float sh[4];
  if (tid < 4) {
    u32 ka, kb;
    if (tid == 0)      { ka = w.k1a; kb = w.k1b; }
    else if (tid == 1) { ka = w.k2a; kb = w.k2b; }
    else if (tid == 2) { ka = w.k3a; kb = w.k3b; }
    else               { ka = w.k4a; kb = w.k4b; }
    sh[tid] = unif_row(ka, kb, row);
  }
  __syncthreads();
  const float r1 = sh[0], r2 = sh[1], u3 = sh[2], p = sh[3];
  // A feeds the |A|>=1 branch decision: match XLA's mul-then-sub (no fma contraction)
  float t2 = (2.0f * w.a) * r1;
  asm volatile("" : "+v"(t2));
  const float A = t2 - w.a;
  const float Cc = 2.0f * r2;
  const float lo = bnd[0], hi = bnd[1];
  const float* pin = pinb + ((size_t)row << 10);
  const int j0 = tid << 2;
  float4 pv = *(const float4*)(pin + j0);
  float ov[4];
  const bool bp = (p < 0.5f);
  if (bp && (fabsf(A) >= 1.0f)) {  // explore: per-element random-row gather
    const u32 fb = ((u32)row << 10) + (u32)j0;
#pragma unroll
    for (int e = 0; e < 4; e++) {
      const float pos = (&pv.x)[e];
      const int ri = ridx_fn(w.k5a, w.k5b, fb + (u32)e);
      const float xr = pinb[((size_t)ri << 10) + j0 + e];
      ov[e] = fabsf(xr - A * fabsf(Cc * xr - pos));
    }
  } else {
    const float* ldp = pinb + ((size_t)w.ldr << 10);
    float4 lv = *(const float4*)(ldp + j0);
    if (bp) {  // exploit
#pragma unroll
      for (int e = 0; e < 4; e++) {
        const float pos = (&pv.x)[e], ld = (&lv.x)[e];
        ov[e] = fabsf(ld - A * fabsf(Cc * ld - pos));
      }
    } else {  // spiral
      const float lp = (w.a2 - 1.0f) * u3 + 1.0f;
      const float s1 = expf(lp);
      const float s2 = cosf(6.2831855f * lp);
#pragma unroll
      for (int e = 0; e < 4; e++) {
        const float pos = (&pv.x)[e], ld = (&lv.x)[e];
        ov[e] = fabsf(fabsf(ld - pos) * s1 * s2 + ld);
      }
    }
  }
  float4 res;
#pragma unroll
  for (int e = 0; e < 4; e++) (&res.x)[e] = fminf(fmaxf(ov[e], lo), hi);
  *(float4*)(poutb + ((size_t)row << 10) + j0) = res;
  if (opt) {
    ushort4 o4;
    o4.x = f2bf(res.x); o4.y = f2bf(res.y); o4.z = f2bf(res.z); o4.w = f2bf(res.w);
    *(ushort4*)(opt + ((size_t)row << 10) + j0) = o4;
  }
}

// ================= host =================
extern "C" void kernel_launch(void* const* d_in, const int* in_sizes, int n_in,
                              void* d_out, int out_size, void* d_ws, size_t ws_size,
                              hipStream_t stream) {
  const float* inp = (const float*)d_in[0];   // input  [8192,1024]
  const float* adj = (const float*)d_in[1];   // adj    [8192,8192]
  const float* h0  = (const float*)d_in[2];   // h0     [8192,1024]
  const float* wgt = (const float*)d_in[3];   // weight [1024,1024]
  const float* lam = (const float*)d_in[4];   // lamda scalar
  const float* alp = (const float*)d_in[5];   // alpha scalar
  const int* lint  = (const int*)d_in[6];     // l scalar
  float* outp = (float*)d_out;

  char* ws = (char*)d_ws;
  float* P0   = (float*)(ws);               // 33.6MB whale ping
  float* P1   = (float*)(ws + 33554432);    // 33.6MB whale pong
  ushort* OPT = (ushort*)(ws + 67108864);   // 16.8MB final positions bf16
  bf16t* B1p  = (bf16t*)(ws + 134217728);   // 16.8MB packed input
  bf16t* Wp   = (bf16t*)(ws + 150994944);   // 2.1MB packed weight
  float* SUP  = (float*)(ws + 153092096);   // 33.6MB support (live to the end)
  float* PRT  = (float*)(ws + 186646528);   // 4KB partials (512 lo + 512 hi)
  float* BND  = (float*)(ws + 186662912);   // lower/upper

  // 1) pack input, weight into MFMA-friendly bf16 layout
  hipLaunchKernelGGL(packb_k, dim3(4096), dim3(256), 0, stream, inp, (uint4*)B1p, 8192, 1024);
  hipLaunchKernelGGL(packb_k, dim3(512), dim3(256), 0, stream, wgt, (uint4*)Wp, 1024, 1024);
  // 2) support = (1-alpha)*(adj@input) + alpha*h0   (adj consumed as f32, + fused min/max)
  hipLaunchKernelGGL((gemm_k<1, 1>), dim3(512), dim3(512), 0, stream, (const void*)adj, B1p, h0, alp, lint,
                     SUP, PRT, 512, 1024, 8192);
  // 3) reduce 512 block partials -> lower/upper
  hipLaunchKernelGGL(minmax2_k, dim3(1), dim3(256), 0, stream, PRT, 512, BND);

  // 4) whale optimizer: key(42) = (0,42); split -> (k0, loop_key)
  u32 k0k[2], lpk[2];
  split2(0u, 42u, k0k, lpk);
  int ldr = scalar_randint8192(k0k[0], k0k[1]);
  const float* cur = SUP;
  float* bufs[2] = {P0, P1};
  for (int it = 0; it < 10; ++it) {
    u32 ka, kb; tf2(lpk[0], lpk[1], 0u, (u32)it, ka, kb);  // fold_in(loop_key, it)
    u32 ks[6][2];
    split6(ka, kb, ks);
    u32 k5A[2], k5B[2];
    split2(ks[4][0], ks[4][1], k5A, k5B);  // randint pre-split: use subkey2
    WA w;
    w.k1a = ks[0][0]; w.k1b = ks[0][1];
    w.k2a = ks[1][0]; w.k2b = ks[1][1];
    w.k3a = ks[2][0]; w.k3b = ks[2][1];
    w.k4a = ks[3][0]; w.k4b = ks[3][1];
    w.k5a = k5B[0];   w.k5b = k5B[1];
    w.ldr = ldr;
    const float itf = (float)it;
    w.a = 2.0f - itf * 0.2f;
    w.a2 = -1.0f + itf * (-0.1f);
    float* nxt = bufs[it & 1];
    hipLaunchKernelGGL(whale_k, dim3(8192), dim3(256), 0, stream, cur, nxt,
                       (it == 9) ? OPT : (ushort*)nullptr, BND, w);
    cur = nxt;
    ldr = scalar_randint8192(ks[5][0], ks[5][1]);  // leader index for next iter
  }
  // 5) out = theta*(opt@weight) + (1-theta)*support
  hipLaunchKernelGGL((gemm_k<2, 0>), dim3(512), dim3(512), 0, stream, (const void*)OPT, Wp, SUP, lam, lint,
                     outp, (float*)nullptr, 0, 1024, 1024);
  (void)in_sizes; (void)n_in; (void)out_size; (void)ws_size;
}